// Round 1
// baseline (123.410 us; speedup 1.0000x reference)
//
#include <hip/hip_runtime.h>

#define BB 8
#define LL 1024
#define DD 512
#define HDIM 4096
#define EPS_LN 1e-5f

// R10: replace the fused kernel's two per-batch spin barriers with STREAM
// ORDERING — 3 kernels, zero atomics, zero poison-semantics reliance.
//
// Evidence: top-5 rocprof dispatches are all fillBufferAligned (~42 us each,
// 256 MiB ws poison @ 80% HBM peak); mha_fused is NOT in the top 5, so the
// kernel is <41.7 us. 118.3 ~= 2x42 (fills, harness-invariant) + ~2.6
// (out restore) + ~31 us kernel. Kernel's own roofline is ~8 us (48 MB
// mandatory HBM traffic). The ~20 us gap matches the R9 observation that
// barrier machinery is the invariant cost: per-wave vmcnt(0) drains at 2
// barriers, s_sleep poll wake latency, 262K device-scope atomic RMWs.
//
// The dependency chain (xs -> T/u -> LN) is exactly what kernel boundaries
// on a stream provide: CP-enforced, ~1-2 us each, overlapped with tail
// drain, with cache coherence guaranteed between dependent launches.
//
// Cost of the split vs fused: x is re-read in K3 (was held in registers) —
// but x is 16 MB and trivially L3-resident (256 MiB MALL) after K1, and only
// 32 MB of weights pass through in between. Partial buffers (512 KB each)
// bounce through L2/L3.
//
// Weight L2 locality preserved in K2: bi = b*32 + j, so the 8 blocks sharing
// chunk j are all == j (mod 8) -> same XCD under round-robin -> 4 chunk-pairs
// x 512 KB = 2 MB per XCD L2 (fits 4 MB). Performance-only assumption.
//
// ws layout: xs_part 256x512 f32 (512 KB) @ 0; u_part 256x512 f32 @ 512 KB.
// Both fully written before read — poison value is never observed.

// ---------------- K1: per-block partial row-sums of x ----------------
// Block bi sums its 32 rows (batch bi>>5, slice bi&31) -> xs_part[bi][512].
__global__ __launch_bounds__(1024) void k_sumx(
    const float* __restrict__ x,
    float* __restrict__ xs_part)
{
    __shared__ float red[16][DD];     // 32 KB
    const int tid  = threadIdx.x;
    const int bi   = blockIdx.x;      // 0..255
    const int dv   = tid & 63;
    const int rowg = tid >> 6;

    const float* basep = x + ((size_t)(bi * 32 + rowg * 2)) * DD + dv * 8;
    float4 a0 = *(const float4*)(basep);
    float4 a1 = *(const float4*)(basep + 4);
    float4 b0 = *(const float4*)(basep + DD);
    float4 b1 = *(const float4*)(basep + DD + 4);

    float4* dst = (float4*)&red[rowg][dv * 8];
    dst[0] = make_float4(a0.x + b0.x, a0.y + b0.y, a0.z + b0.z, a0.w + b0.w);
    dst[1] = make_float4(a1.x + b1.x, a1.y + b1.y, a1.z + b1.z, a1.w + b1.w);
    __syncthreads();

    if (tid < DD) {
        float s = 0.f;
#pragma unroll
        for (int g = 0; g < 16; ++g) s += red[g][tid];
        xs_part[bi * DD + tid] = s;   // plain store — no atomics
    }
}

// ------- K2: T[b, chunk] = xs[b]@wv[:,chunk] + L*bv; u partial via fcw -------
// Block bi = (b = bi>>5, j = bi&31) owns columns c0..c0+127.
__global__ __launch_bounds__(1024) void k_weights(
    const float* __restrict__ wv,
    const float* __restrict__ bv,
    const float* __restrict__ fcw,
    const float* __restrict__ xs_part,
    float* __restrict__ u_part)
{
    __shared__ float xs_b[DD];        // 2 KB
    __shared__ float Tpart[8][128];   // 4 KB
    __shared__ float T_l[128];        // 0.5 KB
    __shared__ float up[2][DD];       // 4 KB

    const int tid = threadIdx.x;
    const int bi  = blockIdx.x;
    const int b   = bi >> 5;
    const int j   = bi & 31;
    const int c0  = j * 128;

    // xs[b] = deterministic tree over the 32 partials (L2-hot, 64 KB/block)
    if (tid < DD) {
        float s = 0.f;
#pragma unroll
        for (int p = 0; p < 32; ++p) s += xs_part[(b * 32 + p) * DD + tid];
        xs_b[tid] = s;
    }
    __syncthreads();

    // T chunk: 8 k-groups x 128 columns
    const int cI = tid & 127;
    const int kg = tid >> 7;
    float t = 0.f;
    const float* wcol = wv + c0 + cI;
#pragma unroll 8
    for (int i = 0; i < 64; ++i) {
        const int k = kg * 64 + i;
        t += xs_b[k] * wcol[(size_t)k * HDIM];
    }
    Tpart[kg][cI] = t;
    __syncthreads();

    if (tid < 128) {
        float s = 0.f;
#pragma unroll
        for (int q = 0; q < 8; ++q) s += Tpart[q][tid];
        T_l[tid] = s + 1024.f * bv[c0 + tid];
    }
    __syncthreads();

    // u partial over my 128 columns: 2 c-groups x 512 d's
    const int dd = tid & 511;
    const int ch = tid >> 9;
    float a = 0.f;
#pragma unroll 8
    for (int i = 0; i < 64; ++i) {
        const int c = ch * 64 + i;
        a += T_l[c] * fcw[(size_t)(c0 + c) * DD + dd];
    }
    up[ch][dd] = a;
    __syncthreads();

    if (tid < DD) u_part[bi * DD + tid] = up[0][tid] + up[1][tid];  // plain store
}

// ---------------- K3: y = LN(x + u + fc_b)*g + beta ----------------
// Block bi handles rows bi*32..+31 of batch b = bi>>5. x comes from L3.
__global__ __launch_bounds__(1024) void k_ln(
    const float* __restrict__ x,
    const float* __restrict__ u_part,
    const float* __restrict__ fcb,
    const float* __restrict__ g,
    const float* __restrict__ beta,
    float* __restrict__ out)
{
    __shared__ float uf[DD];          // 2 KB

    const int tid = threadIdx.x;
    const int bi  = blockIdx.x;
    const int b   = bi >> 5;

    if (tid < DD) {
        float s = 0.f;
#pragma unroll
        for (int p = 0; p < 32; ++p) s += u_part[(b * 32 + p) * DD + tid];
        uf[tid] = s + fcb[tid];
    }
    __syncthreads();

    const int dv   = tid & 63;
    const int rowg = tid >> 6;

    float4 uq0 = *(const float4*)(uf + dv * 8);
    float4 uq1 = *(const float4*)(uf + dv * 8 + 4);
    float4 g0  = *(const float4*)(g + dv * 8);
    float4 g1  = *(const float4*)(g + dv * 8 + 4);
    float4 bt0 = *(const float4*)(beta + dv * 8);
    float4 bt1 = *(const float4*)(beta + dv * 8 + 4);

#pragma unroll
    for (int it = 0; it < 2; ++it) {
        const int row = bi * 32 + rowg * 2 + it;
        const size_t off = (size_t)row * DD + dv * 8;
        float4 x0 = *(const float4*)(x + off);
        float4 x1 = *(const float4*)(x + off + 4);

        float y[8];
        y[0] = x0.x + uq0.x;  y[1] = x0.y + uq0.y;
        y[2] = x0.z + uq0.z;  y[3] = x0.w + uq0.w;
        y[4] = x1.x + uq1.x;  y[5] = x1.y + uq1.y;
        y[6] = x1.z + uq1.z;  y[7] = x1.w + uq1.w;

        float s1 = 0.f, ss = 0.f;
#pragma unroll
        for (int i = 0; i < 8; ++i) { s1 += y[i]; ss += y[i] * y[i]; }
#pragma unroll
        for (int m = 1; m < 64; m <<= 1) {
            s1 += __shfl_xor(s1, m, 64);
            ss += __shfl_xor(ss, m, 64);
        }
        const float mean = s1 * (1.f / 512.f);
        const float var  = ss * (1.f / 512.f) - mean * mean;
        const float rstd = rsqrtf(var + EPS_LN);

        float4 o0, o1;
        o0.x = (y[0] - mean) * rstd * g0.x + bt0.x;
        o0.y = (y[1] - mean) * rstd * g0.y + bt0.y;
        o0.z = (y[2] - mean) * rstd * g0.z + bt0.z;
        o0.w = (y[3] - mean) * rstd * g0.w + bt0.w;
        o1.x = (y[4] - mean) * rstd * g1.x + bt1.x;
        o1.y = (y[5] - mean) * rstd * g1.y + bt1.y;
        o1.z = (y[6] - mean) * rstd * g1.z + bt1.z;
        o1.w = (y[7] - mean) * rstd * g1.w + bt1.w;
        *(float4*)(out + off)     = o0;
        *(float4*)(out + off + 4) = o1;
    }
}

extern "C" void kernel_launch(void* const* d_in, const int* in_sizes, int n_in,
                              void* d_out, int out_size, void* d_ws, size_t ws_size,
                              hipStream_t stream) {
    // setup_inputs order:
    // 0 input, 1 wq, 2 bq, 3 wk, 4 bk, 5 wv, 6 bv, 7 score_w, 8 score_b,
    // 9 fc_w, 10 fc_b, 11 ln_g, 12 ln_b
    // (wq/bq/wk/bk/score_* are dead: softmax over a size-1 axis == 1.)
    const float* x   = (const float*)d_in[0];
    const float* wv  = (const float*)d_in[5];
    const float* bv  = (const float*)d_in[6];
    const float* fcw = (const float*)d_in[9];
    const float* fcb = (const float*)d_in[10];
    const float* lng = (const float*)d_in[11];
    const float* lnb = (const float*)d_in[12];

    float* xs_part = (float*)d_ws;                         // 512 KB @ 0
    float* u_part  = (float*)((char*)d_ws + 512 * 1024);   // 512 KB
    float* out     = (float*)d_out;

    // Dependencies enforced by stream order — no barriers, no atomics.
    k_sumx   <<<256, 1024, 0, stream>>>(x, xs_part);
    k_weights<<<256, 1024, 0, stream>>>(wv, bv, fcw, xs_part, u_part);
    k_ln     <<<256, 1024, 0, stream>>>(x, u_part, fcb, lng, lnb, out);
}